// Round 7
// baseline (175.714 us; speedup 1.0000x reference)
//
#include <hip/hip_runtime.h>
#include <math.h>

typedef unsigned long long u64;

#define BATCH 16
#define NBOX 100000
#define NCLS 30
#define K 200            // PRE_NMS_TOPK
#define MAXDET 100
#define SCORE_THR 0.01f
#define NMS_THR 0.5f
#define T0 0.995f        // static collect threshold; inline fallback guarantees exactness

#define ELEM_PER_BATCH (NBOX * NCLS)              // 3,000,000
#define CAP 1024
#define CHUNKS 48                                 // chunks per batch
#define VEC_PER_CHUNK 15625                       // 750000 vec4 per batch / 48
#define LDS_CAP 48                                // per-class per-block hit buffer

// workspace layout (bytes)
#define OFF_COLL   0ull                                            // u64[480*CAP]
#define OFF_CNT    (OFF_COLL + (size_t)BATCH*NCLS*CAP*8)           // int[480] + int[16] bcnt + pad
#define OFF_WSI    (OFF_CNT + 512*4)                               // int[480*200]
#define OFF_MERGE  (OFF_WSI + (size_t)BATCH*NCLS*K*4)              // u64[16][32][128]

// ---------------------------------------------------------------------------
// 1) Single coalesced pass: collect entries > T0. Hits staged in per-class
//    LDS buffers (LDS atomics only); ONE global atomicAdd per (class,block).
//    2-way unrolled loads for latency hiding.
// ---------------------------------------------------------------------------
__global__ __launch_bounds__(512) void collect_kernel(const float* __restrict__ cls,
                                                      int* __restrict__ cnt,
                                                      u64* __restrict__ coll) {
  const int b = blockIdx.x / CHUNKS;
  const int chunk = blockIdx.x % CHUNKS;
  const int tid = threadIdx.x;

  __shared__ u64 lbuf[NCLS][LDS_CAP];
  __shared__ int lcnt[NCLS];
  __shared__ int lbase[NCLS];

  if (tid < NCLS) lcnt[tid] = 0;
  __syncthreads();

  const int vbase = chunk * VEC_PER_CHUNK;   // vec4 index within batch
  const float4* p = (const float4*)(cls + (size_t)b * ELEM_PER_BATCH) + vbase;

  auto process = [&](float4 v, int idx) {
    float m = fmaxf(fmaxf(v.x, v.y), fmaxf(v.z, v.w));
    if (m > T0) {                            // rare (~2% of vec4s)
      float vv[4] = {v.x, v.y, v.z, v.w};
      #pragma unroll
      for (int j = 0; j < 4; ++j) {
        if (vv[j] > T0) {
          int e = (vbase + idx) * 4 + j;     // element within batch (< 3M)
          int c = e % NCLS;
          int n = e / NCLS;
          int pos = atomicAdd(&lcnt[c], 1);  // LDS atomic — cheap
          if (pos < LDS_CAP)
            lbuf[c][pos] = ((u64)__float_as_uint(vv[j]) << 32) | (unsigned)(~(unsigned)n);
        }
      }
    }
  };

  int i = tid;
  for (; i + 512 < VEC_PER_CHUNK; i += 1024) {
    float4 a = p[i];
    float4 b2 = p[i + 512];
    process(a, i);
    process(b2, i + 512);
  }
  if (i < VEC_PER_CHUNK) process(p[i], i);
  __syncthreads();

  if (tid < NCLS) {
    int m = lcnt[tid];
    int stored = (m < LDS_CAP) ? m : LDS_CAP;
    int bump = (m > LDS_CAP) ? 1000000 : 0;  // force cnt>CAP -> exact fallback path
    int base = atomicAdd(&cnt[b * NCLS + tid], m + bump);
    lbase[tid] = base;
    lcnt[tid] = stored;
  }
  __syncthreads();

  for (int t = tid; t < NCLS * LDS_CAP; t += 512) {
    int c = t / LDS_CAP, s = t - (t / LDS_CAP) * LDS_CAP;
    if (s < lcnt[c]) {
      int slot = lbase[c] + s;
      if (slot < CAP)
        coll[(size_t)(b * NCLS + c) * CAP + slot] = lbuf[c][s];
    }
  }
}

// ---------------------------------------------------------------------------
// 2) Fused: sort -> top-200 -> bitmask NMS -> compaction -> merged emission.
//    Last block per batch (atomic counter) runs the merge tournament + gather.
//    Bad (b,c) [cnt<K or cnt>CAP]: inline exact radix-select from cls.
// ---------------------------------------------------------------------------
__global__ __launch_bounds__(512) void fused_sort_nms_kernel(
    const u64* __restrict__ coll, const int* __restrict__ cnt,
    const float* __restrict__ cls, const float* __restrict__ boxes,
    const float* __restrict__ rot, const float* __restrict__ tr,
    int* __restrict__ ws_i, u64* __restrict__ merged,
    int* __restrict__ bcnt, float* __restrict__ out) {
  const int bc = blockIdx.x;
  const int b = bc / NCLS, c = bc % NCLS;
  const int tid = threadIdx.x;

  // 32KB pool; phase-1 arrays (<=24KB) overlay the merge-phase W (32KB)
  __shared__ char pool[32768] __attribute__((aligned(16)));
  u64*      arr   = (u64*)pool;                          // [1024]   8192 B
  float4*   sbox  = (float4*)(pool + 8192);              // [200]    3200 B
  float*    sarea = (float*)(pool + 11392);              // [200]     800 B
  float*    ss    = (float*)(pool + 12192);              // [200]     800 B
  int*      sidx  = (int*)(pool + 12992);                // [200]     800 B
  unsigned (*mask)[8] = (unsigned (*)[8])(pool + 13792); // [200][8] 6400 B
  u64*      comb  = (u64*)(pool + 20192);                // [256]    2048 B
  unsigned* eqbuf = (unsigned*)(pool + 22240);           // [512]    2048 B
  u64*      W     = (u64*)pool;                          // [4096]  32768 B (merge)

  __shared__ unsigned keepw[8];
  __shared__ int s_surv, s_last;
  __shared__ unsigned s_pref, s_mask, s_krem, s_takeall;
  __shared__ unsigned s_cntgt, s_cnteq;

  const int ct = cnt[bc];
  const bool bad = (ct < K) || (ct > CAP);
  if (!bad) {
    for (int i = tid; i < CAP; i += 512)
      arr[i] = (i < ct) ? coll[(size_t)bc * CAP + i] : 0ull;
    for (int k = 2; k <= CAP; k <<= 1) {
      for (int j = k >> 1; j > 0; j >>= 1) {
        __syncthreads();
        for (int i = tid; i < CAP; i += 512) {
          int l = i ^ j;
          if (l > i) {
            u64 a = arr[i], bb = arr[l];
            bool up = ((i & k) == 0);
            if (up ? (a < bb) : (a > bb)) { arr[i] = bb; arr[l] = a; }
          }
        }
      }
    }
    __syncthreads();
    for (int r = tid; r < K; r += 512) {
      u64 e = arr[r];
      float s = (e != 0ull) ? __uint_as_float((unsigned)(e >> 32)) : -INFINITY;
      int idx = (e != 0ull) ? (int)(~(unsigned)e) : 0;
      ss[r] = s; sidx[r] = idx;
      ws_i[bc * K + r] = idx;
    }
  } else {
    // ---- inline exact radix select over the strided class column ----
    unsigned (*hist)[256] = (unsigned (*)[256])arr;   // 8 x 256 = 8KB
    const int wv = tid >> 6;
    if (tid == 0) { s_pref = 0u; s_mask = 0u; s_krem = K; s_takeall = 0u; }
    __syncthreads();
    const float* col = cls + (size_t)b * NBOX * NCLS + c;

    for (int pass = 0; pass < 4; ++pass) {
      if (s_takeall) break;
      const int shift = 24 - 8 * pass;
      for (int i = tid; i < 8 * 256; i += 512) ((unsigned*)hist)[i] = 0u;
      __syncthreads();
      const unsigned pref = s_pref, msk = s_mask;
      for (int n = tid; n < NBOX; n += 512) {
        float v = col[(size_t)n * NCLS];
        if (v > SCORE_THR) {
          unsigned key = __float_as_uint(v);
          if ((key & msk) == pref)
            atomicAdd(&hist[wv][(key >> shift) & 0xFFu], 1u);
        }
      }
      __syncthreads();
      if (tid < 256) {
        unsigned t2 = 0;
        for (int w = 0; w < 8; ++w) t2 += hist[w][tid];
        hist[0][tid] = t2;
      }
      __syncthreads();
      if (tid == 0) {
        unsigned krem = s_krem, cum = 0; int dsel = -1;
        for (int d = 255; d >= 0; --d) {
          unsigned cc = hist[0][d];
          if (cum + cc >= krem) { dsel = d; break; }
          cum += cc;
        }
        if (dsel < 0) s_takeall = 1u;
        else {
          s_krem = krem - cum;
          s_pref = pref | ((unsigned)dsel << shift);
          s_mask = msk | (0xFFu << shift);
        }
      }
      __syncthreads();
    }

    if (tid == 0) { s_cntgt = 0u; s_cnteq = 0u; }
    __syncthreads();
    const unsigned pivot = s_pref;
    const unsigned takeall = s_takeall;

    for (int n = tid; n < NBOX; n += 512) {
      float v = col[(size_t)n * NCLS];
      if (v > SCORE_THR) {
        unsigned key = __float_as_uint(v);
        if (takeall || key > pivot) {
          unsigned pos = atomicAdd(&s_cntgt, 1u);
          if (pos < 256u)
            comb[pos] = ((u64)key << 32) | (unsigned)(~(unsigned)n);
        } else if (key == pivot) {
          unsigned pos = atomicAdd(&s_cnteq, 1u);
          if (pos < 512u) eqbuf[pos] = (unsigned)n;
        }
      }
    }
    __syncthreads();
    const unsigned cntgt = (s_cntgt < 256u) ? s_cntgt : 256u;
    const unsigned cnteq = (s_cnteq < 512u) ? s_cnteq : 512u;
    unsigned need = 0;
    if (!takeall) {
      need = (cntgt < (unsigned)K) ? ((unsigned)K - cntgt) : 0u;
      if (need > cnteq) need = cnteq;
    }
    for (int i = tid; i < 512; i += 512)
      if ((unsigned)i >= cnteq) eqbuf[i] = 0xFFFFFFFFu;
    for (int k = 2; k <= 512; k <<= 1) {
      for (int j = k >> 1; j > 0; j >>= 1) {
        __syncthreads();
        {
          int i = tid, l = i ^ j;
          if (l > i && i < 512) {
            unsigned a = eqbuf[i], bb = eqbuf[l];
            bool up = ((i & k) == 0);
            if (up ? (a > bb) : (a < bb)) { eqbuf[i] = bb; eqbuf[l] = a; }
          }
        }
      }
    }
    __syncthreads();
    for (int t = tid; t < (int)need; t += 512)
      comb[cntgt + t] = ((u64)pivot << 32) | (unsigned)(~eqbuf[t]);
    const unsigned M = cntgt + need;
    for (int i = tid; i < 256; i += 512)
      if ((unsigned)i >= M) comb[i] = 0ull;
    for (int k = 2; k <= 256; k <<= 1) {
      for (int j = k >> 1; j > 0; j >>= 1) {
        __syncthreads();
        if (tid < 256) {
          int i = tid, l = i ^ j;
          if (l > i) {
            u64 a = comb[i], bb = comb[l];
            bool up = ((i & k) == 0);
            if (up ? (a < bb) : (a > bb)) { comb[i] = bb; comb[l] = a; }
          }
        }
      }
    }
    __syncthreads();
    if (tid < K) {
      if ((unsigned)tid < M) {
        u64 e = comb[tid];
        ss[tid] = __uint_as_float((unsigned)(e >> 32));
        sidx[tid] = (int)(~(unsigned)e);
      } else {
        ss[tid] = -INFINITY;
        sidx[tid] = 0;
      }
      ws_i[bc * K + tid] = sidx[tid];
    }
  }

  for (int i = tid; i < K * 8; i += 512) ((unsigned*)mask)[i] = 0u;
  if (tid < 8) keepw[tid] = 0u;
  __syncthreads();

  for (int r = tid; r < K; r += 512) {
    float s = ss[r];
    bool valid = (s != -INFINITY);
    float x1 = 0.f, y1 = 0.f, x2 = 0.f, y2 = 0.f;
    if (valid) {
      const float* bp = boxes + ((size_t)b * NBOX + sidx[r]) * 4;
      x1 = bp[0]; y1 = bp[1]; x2 = bp[2]; y2 = bp[3];
      atomicOr(&keepw[r >> 5], 1u << (r & 31));
    }
    sbox[r] = make_float4(x1, y1, x2, y2);
    sarea[r] = fmaxf(x2 - x1, 0.f) * fmaxf(y2 - y1, 0.f);
  }
  __syncthreads();

  // pairwise suppression bitmask: j (=tid&255, register-resident box) vs
  // broadcast row i = (tid>>8) + 2k. No int div, 2 LDS broadcasts per row.
  {
    const int jj = tid & 255;
    const bool jvalid = (jj < K);
    float jx1 = 0.f, jy1 = 0.f, jx2 = 0.f, jy2 = 0.f, ja = 0.f;
    if (jvalid) {
      float4 jb = sbox[jj];
      jx1 = jb.x; jy1 = jb.y; jx2 = jb.z; jy2 = jb.w;
      ja = sarea[jj];
    }
    #pragma unroll 4
    for (int k2 = 0; k2 < K / 2; ++k2) {
      int i = (tid >> 8) + 2 * k2;
      float4 ib = sbox[i];         // broadcast (same addr across lanes)
      float ia = sarea[i];
      if (jvalid && jj > i) {
        float xx1 = fmaxf(ib.x, jx1);
        float yy1 = fmaxf(ib.y, jy1);
        float xx2 = fminf(ib.z, jx2);
        float yy2 = fminf(ib.w, jy2);
        float inter = fmaxf(xx2 - xx1, 0.f) * fmaxf(yy2 - yy1, 0.f);
        float uni = ia + ja - inter;
        float iou = inter / fmaxf(uni, 1e-8f);
        if (iou > NMS_THR) atomicOr(&mask[i][jj >> 5], 1u << (jj & 31));
      }
    }
  }
  __syncthreads();

  // serial greedy scan on wave 0 (wave-synchronous, no barriers)
  if (tid < 64) {
    int w = tid & 7;
    unsigned keep = keepw[w];
    for (int i = 0; i < K; ++i) {
      unsigned kw = __shfl(keep, i >> 5, 64);
      if ((kw >> (i & 31)) & 1u)
        keep &= ~mask[i][w];
    }
    if (tid < 8) keepw[tid] = keep;
  }
  __syncthreads();

  // stable compaction + key emission (per-class list is sorted desc by key)
  for (int r = tid; r < K; r += 512) {
    int w6 = r >> 5, bit = r & 31;
    if ((keepw[w6] >> bit) & 1u) {
      int pos = 0;
      #pragma unroll
      for (int w = 0; w < 7; ++w) {
        unsigned kw = keepw[w];
        if (w < w6) pos += __popc(kw);
        else if (w == w6) pos += __popc(kw & ((1u << bit) - 1u));
      }
      if (pos < 128) {
        unsigned ord = __float_as_uint(ss[r]) | 0x80000000u;
        merged[((size_t)b * 32 + c) * 128 + pos] =
          ((u64)ord << 32) | (unsigned)(~(unsigned)(c * K + r));
      }
    }
  }
  if (tid == 0) {
    int S = 0;
    #pragma unroll
    for (int w = 0; w < 7; ++w) S += __popc(keepw[w]);
    s_surv = S;
  }
  __syncthreads();
  for (int t = s_surv + tid; t < 128; t += 512)
    merged[((size_t)b * 32 + c) * 128 + t] = 0ull;

  // ---- last block of this batch runs the merge tournament + gather ----
  __syncthreads();
  __threadfence();                                  // release: flush merged/ws_i
  if (tid == 0)
    s_last = (atomicAdd(&bcnt[b], 1) == NCLS - 1) ? 1 : 0;
  __syncthreads();
  if (!s_last) return;
  __threadfence();                                  // acquire: invalidate stale L2

  for (int t = tid; t < 4096; t += 512) {
    int c2 = t >> 7, r = t & 127;
    W[t] = (c2 < NCLS) ? merged[((size_t)b * 32 + c2) * 128 + r] : 0ull;
  }
  __syncthreads();

  int active = 4096;
  for (int level = 0; level < 5; ++level) {
    int npairs = active >> 8;
    for (int t = tid; t < npairs * 64; t += 512) {
      int p = t >> 6, q = t & 63;
      int i1 = p * 256 + 128 + q, i2 = p * 256 + 255 - q;
      u64 a = W[i1]; W[i1] = W[i2]; W[i2] = a;
    }
    __syncthreads();
    for (int j = 128; j > 0; j >>= 1) {
      for (int i = tid; i < active; i += 512) {
        int l = i ^ j;
        if (l > i) {
          u64 a = W[i], bb = W[l];
          if (a < bb) { W[i] = bb; W[l] = a; }
        }
      }
      __syncthreads();
    }
    int half = active >> 1;
    u64 v0 = 0, v1 = 0, v2 = 0, v3 = 0;
    { int t = tid;        if (t < half) v0 = W[(t >> 7) * 256 + (t & 127)]; }
    { int t = tid + 512;  if (t < half) v1 = W[(t >> 7) * 256 + (t & 127)]; }
    { int t = tid + 1024; if (t < half) v2 = W[(t >> 7) * 256 + (t & 127)]; }
    { int t = tid + 1536; if (t < half) v3 = W[(t >> 7) * 256 + (t & 127)]; }
    __syncthreads();
    { int t = tid;        if (t < half) W[t] = v0; }
    { int t = tid + 512;  if (t < half) W[t] = v1; }
    { int t = tid + 1024; if (t < half) W[t] = v2; }
    { int t = tid + 1536; if (t < half) W[t] = v3; }
    __syncthreads();
    active = half;
  }

  if (tid < MAXDET) {
    u64 key = W[tid];
    bool valid = (key != 0ull);
    float* ob  = out + ((size_t)b * MAXDET + tid) * 4;
    float* os  = out + (size_t)BATCH * MAXDET * 4 + b * MAXDET + tid;
    float* ol  = os + BATCH * MAXDET;
    float* orr = out + (size_t)BATCH * MAXDET * 6 + ((size_t)b * MAXDET + tid) * 3;
    float* ot  = orr + (size_t)BATCH * MAXDET * 3;

    if (valid) {
      unsigned f = ~(unsigned)key;            // flat = c*K + r
      int cl = (int)(f / K);
      float sc = __uint_as_float((unsigned)(key >> 32) & 0x7FFFFFFFu);
      int orig = ws_i[(size_t)b * NCLS * K + f];
      const float* bp = boxes + ((size_t)b * NBOX + orig) * 4;
      ob[0] = bp[0]; ob[1] = bp[1]; ob[2] = bp[2]; ob[3] = bp[3];
      *os = sc;
      *ol = (float)cl;
      const float* rp = rot + ((size_t)b * NBOX + orig) * 3;
      orr[0] = rp[0]; orr[1] = rp[1]; orr[2] = rp[2];
      const float* tp = tr + ((size_t)b * NBOX + orig) * 3;
      ot[0] = tp[0]; ot[1] = tp[1]; ot[2] = tp[2];
    } else {
      ob[0] = ob[1] = ob[2] = ob[3] = -1.f;
      *os = -1.f; *ol = -1.f;
      orr[0] = orr[1] = orr[2] = -1.f;
      ot[0] = ot[1] = ot[2] = -1.f;
    }
  }
}

extern "C" void kernel_launch(void* const* d_in, const int* in_sizes, int n_in,
                              void* d_out, int out_size, void* d_ws, size_t ws_size,
                              hipStream_t stream) {
  const float* boxes = (const float*)d_in[0];
  const float* cls   = (const float*)d_in[1];
  const float* rot   = (const float*)d_in[2];
  const float* tr    = (const float*)d_in[3];
  float* out = (float*)d_out;

  char* ws = (char*)d_ws;
  u64*   coll   = (u64*)(ws + OFF_COLL);
  int*   cnt    = (int*)(ws + OFF_CNT);        // [480]
  int*   bcnt   = cnt + BATCH * NCLS;          // [16]
  int*   ws_i   = (int*)(ws + OFF_WSI);
  u64*   merged = (u64*)(ws + OFF_MERGE);

  hipMemsetAsync(cnt, 0, 512 * sizeof(int), stream);   // cnt + bcnt
  collect_kernel<<<BATCH * CHUNKS, 512, 0, stream>>>(cls, cnt, coll);
  fused_sort_nms_kernel<<<BATCH * NCLS, 512, 0, stream>>>(coll, cnt, cls, boxes,
                                                          rot, tr, ws_i, merged,
                                                          bcnt, out);
}

// Round 8
// 117.342 us; speedup vs baseline: 1.4975x; 1.4975x over previous
//
#include <hip/hip_runtime.h>
#include <math.h>

typedef unsigned long long u64;

#define BATCH 16
#define NBOX 100000
#define NCLS 30
#define K 200            // PRE_NMS_TOPK
#define MAXDET 100
#define SCORE_THR 0.01f
#define NMS_THR 0.5f
#define T0 0.995f        // static collect threshold; inline fallback guarantees exactness

#define ELEM_PER_BATCH (NBOX * NCLS)              // 3,000,000
#define CAP 1024
#define CHUNKS 48                                 // chunks per batch
#define VEC_PER_CHUNK 15625                       // 750000 vec4 per batch / 48
#define LDS_CAP 48                                // per-class per-block hit buffer

// workspace layout (bytes)
#define OFF_COLL   0ull                                            // u64[480*CAP]
#define OFF_CNT    (OFF_COLL + (size_t)BATCH*NCLS*CAP*8)           // int[480] (+pad)
#define OFF_WSI    (OFF_CNT + 512*4)                               // int[480*200]
#define OFF_MERGE  (OFF_WSI + (size_t)BATCH*NCLS*K*4)              // u64[16][32][128]

// ---------------------------------------------------------------------------
// 1) Single coalesced pass: collect entries > T0. Hits staged in per-class
//    LDS buffers (LDS atomics only); ONE global atomicAdd per (class,block).
//    4-deep register load batching for memory-level parallelism.
// ---------------------------------------------------------------------------
__global__ __launch_bounds__(512) void collect_kernel(const float* __restrict__ cls,
                                                      int* __restrict__ cnt,
                                                      u64* __restrict__ coll) {
  const int b = blockIdx.x / CHUNKS;
  const int chunk = blockIdx.x % CHUNKS;
  const int tid = threadIdx.x;

  __shared__ u64 lbuf[NCLS][LDS_CAP];
  __shared__ int lcnt[NCLS];
  __shared__ int lbase[NCLS];

  if (tid < NCLS) lcnt[tid] = 0;
  __syncthreads();

  const int vbase = chunk * VEC_PER_CHUNK;   // vec4 index within batch
  const float4* p = (const float4*)(cls + (size_t)b * ELEM_PER_BATCH) + vbase;

  auto process = [&](float4 v, int idx) {
    float m = fmaxf(fmaxf(v.x, v.y), fmaxf(v.z, v.w));
    if (m > T0) {                            // rare (~2% of vec4s)
      float vv[4] = {v.x, v.y, v.z, v.w};
      #pragma unroll
      for (int j = 0; j < 4; ++j) {
        if (vv[j] > T0) {
          int e = (vbase + idx) * 4 + j;     // element within batch (< 3M)
          int c = e % NCLS;
          int n = e / NCLS;
          int pos = atomicAdd(&lcnt[c], 1);  // LDS atomic — cheap
          if (pos < LDS_CAP)
            lbuf[c][pos] = ((u64)__float_as_uint(vv[j]) << 32) | (unsigned)(~(unsigned)n);
        }
      }
    }
  };

  int i = tid;
  for (; i + 1536 < VEC_PER_CHUNK; i += 2048) {
    float4 a  = p[i];
    float4 b2 = p[i + 512];
    float4 c2 = p[i + 1024];
    float4 d2 = p[i + 1536];
    process(a,  i);
    process(b2, i + 512);
    process(c2, i + 1024);
    process(d2, i + 1536);
  }
  for (; i < VEC_PER_CHUNK; i += 512) process(p[i], i);
  __syncthreads();

  if (tid < NCLS) {
    int m = lcnt[tid];
    int stored = (m < LDS_CAP) ? m : LDS_CAP;
    int bump = (m > LDS_CAP) ? 1000000 : 0;  // force cnt>CAP -> exact fallback path
    int base = atomicAdd(&cnt[b * NCLS + tid], m + bump);
    lbase[tid] = base;
    lcnt[tid] = stored;
  }
  __syncthreads();

  for (int t = tid; t < NCLS * LDS_CAP; t += 512) {
    int c = t / LDS_CAP, s = t - (t / LDS_CAP) * LDS_CAP;
    if (s < lcnt[c]) {
      int slot = lbase[c] + s;
      if (slot < CAP)
        coll[(size_t)(b * NCLS + c) * CAP + slot] = lbuf[c][s];
    }
  }
}

// ---------------------------------------------------------------------------
// 2) Fused: sort candidates -> top-200 -> bitmask NMS -> stable compaction ->
//    emit sorted per-class key list (top-128) for the merge tournament.
//    Sort width adapts: 512 when ct<=512 (common), else 1024.
//    Bad (b,c) [cnt<K or cnt>CAP]: inline exact radix-select from cls.
// ---------------------------------------------------------------------------
__global__ __launch_bounds__(512) void fused_sort_nms_kernel(
    const u64* __restrict__ coll, const int* __restrict__ cnt,
    const float* __restrict__ cls, const float* __restrict__ boxes,
    int* __restrict__ ws_i, u64* __restrict__ merged) {
  const int bc = blockIdx.x;
  const int b = bc / NCLS, c = bc % NCLS;
  const int tid = threadIdx.x;

  __shared__ u64 arr[CAP];                 // good path: sort buffer; bad path: hist overlay
  __shared__ float sx1[K], sy1[K], sx2[K], sy2[K], sarea[K], ss[K];
  __shared__ int sidx[K];
  __shared__ unsigned mask[K][8];
  __shared__ unsigned keepw[8];
  __shared__ int s_surv;
  __shared__ u64 comb[256];
  __shared__ unsigned eqbuf[512];
  __shared__ unsigned s_pref, s_mask, s_krem, s_takeall;
  __shared__ unsigned s_cntgt, s_cnteq;

  const int ct = cnt[bc];
  const bool bad = (ct < K) || (ct > CAP);
  if (!bad) {
    const int N = (ct <= 512) ? 512 : CAP;   // block-uniform -> barrier-safe
    for (int i = tid; i < N; i += 512)
      arr[i] = (i < ct) ? coll[(size_t)bc * CAP + i] : 0ull;
    for (int k = 2; k <= N; k <<= 1) {
      for (int j = k >> 1; j > 0; j >>= 1) {
        __syncthreads();
        for (int i = tid; i < N; i += 512) {
          int l = i ^ j;
          if (l > i) {
            u64 a = arr[i], bb = arr[l];
            bool up = ((i & k) == 0);
            if (up ? (a < bb) : (a > bb)) { arr[i] = bb; arr[l] = a; }
          }
        }
      }
    }
    __syncthreads();
    for (int r = tid; r < K; r += 512) {
      u64 e = arr[r];
      float s = (e != 0ull) ? __uint_as_float((unsigned)(e >> 32)) : -INFINITY;
      int idx = (e != 0ull) ? (int)(~(unsigned)e) : 0;
      ss[r] = s; sidx[r] = idx;
      ws_i[bc * K + r] = idx;
    }
  } else {
    // ---- inline exact radix select over the strided class column ----
    unsigned (*hist)[256] = (unsigned (*)[256])arr;   // 8 waves x 256 bins = 8KB
    const int wv = tid >> 6;
    if (tid == 0) { s_pref = 0u; s_mask = 0u; s_krem = K; s_takeall = 0u; }
    __syncthreads();
    const float* col = cls + (size_t)b * NBOX * NCLS + c;

    for (int pass = 0; pass < 4; ++pass) {
      if (s_takeall) break;
      const int shift = 24 - 8 * pass;
      for (int i = tid; i < 8 * 256; i += 512) ((unsigned*)hist)[i] = 0u;
      __syncthreads();
      const unsigned pref = s_pref, msk = s_mask;
      for (int n = tid; n < NBOX; n += 512) {
        float v = col[(size_t)n * NCLS];
        if (v > SCORE_THR) {
          unsigned key = __float_as_uint(v);
          if ((key & msk) == pref)
            atomicAdd(&hist[wv][(key >> shift) & 0xFFu], 1u);
        }
      }
      __syncthreads();
      if (tid < 256) {
        unsigned t2 = 0;
        for (int w = 0; w < 8; ++w) t2 += hist[w][tid];
        hist[0][tid] = t2;
      }
      __syncthreads();
      if (tid == 0) {
        unsigned krem = s_krem, cum = 0; int dsel = -1;
        for (int d = 255; d >= 0; --d) {
          unsigned cc = hist[0][d];
          if (cum + cc >= krem) { dsel = d; break; }
          cum += cc;
        }
        if (dsel < 0) s_takeall = 1u;
        else {
          s_krem = krem - cum;
          s_pref = pref | ((unsigned)dsel << shift);
          s_mask = msk | (0xFFu << shift);
        }
      }
      __syncthreads();
    }

    if (tid == 0) { s_cntgt = 0u; s_cnteq = 0u; }
    __syncthreads();
    const unsigned pivot = s_pref;
    const unsigned takeall = s_takeall;

    for (int n = tid; n < NBOX; n += 512) {
      float v = col[(size_t)n * NCLS];
      if (v > SCORE_THR) {
        unsigned key = __float_as_uint(v);
        if (takeall || key > pivot) {
          unsigned pos = atomicAdd(&s_cntgt, 1u);
          if (pos < 256u)
            comb[pos] = ((u64)key << 32) | (unsigned)(~(unsigned)n);
        } else if (key == pivot) {
          unsigned pos = atomicAdd(&s_cnteq, 1u);
          if (pos < 512u) eqbuf[pos] = (unsigned)n;
        }
      }
    }
    __syncthreads();
    const unsigned cntgt = (s_cntgt < 256u) ? s_cntgt : 256u;
    const unsigned cnteq = (s_cnteq < 512u) ? s_cnteq : 512u;
    unsigned need = 0;
    if (!takeall) {
      need = (cntgt < (unsigned)K) ? ((unsigned)K - cntgt) : 0u;
      if (need > cnteq) need = cnteq;
    }
    for (int i = tid; i < 512; i += 512)
      if ((unsigned)i >= cnteq) eqbuf[i] = 0xFFFFFFFFu;
    for (int k = 2; k <= 512; k <<= 1) {
      for (int j = k >> 1; j > 0; j >>= 1) {
        __syncthreads();
        {
          int i = tid, l = i ^ j;
          if (l > i) {
            unsigned a = eqbuf[i], bb = eqbuf[l];
            bool up = ((i & k) == 0);
            if (up ? (a > bb) : (a < bb)) { eqbuf[i] = bb; eqbuf[l] = a; }
          }
        }
      }
    }
    __syncthreads();
    for (int t = tid; t < (int)need; t += 512)
      comb[cntgt + t] = ((u64)pivot << 32) | (unsigned)(~eqbuf[t]);
    const unsigned M = cntgt + need;
    for (int i = tid; i < 256; i += 512)
      if ((unsigned)i >= M) comb[i] = 0ull;
    for (int k = 2; k <= 256; k <<= 1) {
      for (int j = k >> 1; j > 0; j >>= 1) {
        __syncthreads();
        if (tid < 256) {
          int i = tid, l = i ^ j;
          if (l > i) {
            u64 a = comb[i], bb = comb[l];
            bool up = ((i & k) == 0);
            if (up ? (a < bb) : (a > bb)) { comb[i] = bb; comb[l] = a; }
          }
        }
      }
    }
    __syncthreads();
    if (tid < K) {
      if ((unsigned)tid < M) {
        u64 e = comb[tid];
        ss[tid] = __uint_as_float((unsigned)(e >> 32));
        sidx[tid] = (int)(~(unsigned)e);
      } else {
        ss[tid] = -INFINITY;
        sidx[tid] = 0;
      }
      ws_i[bc * K + tid] = sidx[tid];
    }
  }
  for (int i = tid; i < K * 8; i += 512) ((unsigned*)mask)[i] = 0u;
  if (tid < 8) keepw[tid] = 0u;
  __syncthreads();

  for (int r = tid; r < K; r += 512) {
    float s = ss[r];
    bool valid = (s != -INFINITY);
    float x1 = 0.f, y1 = 0.f, x2 = 0.f, y2 = 0.f;
    if (valid) {
      const float* bp = boxes + ((size_t)b * NBOX + sidx[r]) * 4;
      x1 = bp[0]; y1 = bp[1]; x2 = bp[2]; y2 = bp[3];
      atomicOr(&keepw[r >> 5], 1u << (r & 31));
    }
    sx1[r] = x1; sy1[r] = y1; sx2[r] = x2; sy2[r] = y2;
    sarea[r] = fmaxf(x2 - x1, 0.f) * fmaxf(y2 - y1, 0.f);
  }
  __syncthreads();

  // pairwise suppression bitmask, j > i (fully parallel, no barriers)
  for (int t = tid; t < K * K; t += 512) {
    int i = t / K, j = t - i * K;
    if (j > i) {
      float xx1 = fmaxf(sx1[i], sx1[j]);
      float yy1 = fmaxf(sy1[i], sy1[j]);
      float xx2 = fminf(sx2[i], sx2[j]);
      float yy2 = fminf(sy2[i], sy2[j]);
      float inter = fmaxf(xx2 - xx1, 0.f) * fmaxf(yy2 - yy1, 0.f);
      float uni = sarea[i] + sarea[j] - inter;
      float iou = inter / fmaxf(uni, 1e-8f);
      if (iou > NMS_THR) atomicOr(&mask[i][j >> 5], 1u << (j & 31));
    }
  }
  __syncthreads();

  // serial greedy scan on wave 0 (wave-synchronous, no barriers)
  if (tid < 64) {
    int w = tid & 7;
    unsigned keep = keepw[w];
    for (int i = 0; i < K; ++i) {
      unsigned kw = __shfl(keep, i >> 5, 64);
      if ((kw >> (i & 31)) & 1u)
        keep &= ~mask[i][w];
    }
    if (tid < 8) keepw[tid] = keep;
  }
  __syncthreads();

  // stable compaction + key emission (per-class list is sorted desc by key)
  for (int r = tid; r < K; r += 512) {
    int w6 = r >> 5, bit = r & 31;
    if ((keepw[w6] >> bit) & 1u) {
      int pos = 0;
      #pragma unroll
      for (int w = 0; w < 7; ++w) {
        unsigned kw = keepw[w];
        if (w < w6) pos += __popc(kw);
        else if (w == w6) pos += __popc(kw & ((1u << bit) - 1u));
      }
      if (pos < 128) {
        unsigned ord = __float_as_uint(ss[r]) | 0x80000000u;
        merged[((size_t)b * 32 + c) * 128 + pos] =
          ((u64)ord << 32) | (unsigned)(~(unsigned)(c * K + r));
      }
    }
  }
  if (tid == 0) {
    int S = 0;
    #pragma unroll
    for (int w = 0; w < 7; ++w) S += __popc(keepw[w]);
    s_surv = S;
  }
  __syncthreads();
  for (int t = s_surv + tid; t < 128; t += 512)
    merged[((size_t)b * 32 + c) * 128 + t] = 0ull;
}

// ---------------------------------------------------------------------------
// 3) Per-image merge tournament: 32 sorted lists of 128 -> top-128 -> gather.
// ---------------------------------------------------------------------------
__global__ __launch_bounds__(1024) void merge_gather_kernel(
    const u64* __restrict__ merged, const int* __restrict__ ws_i,
    const float* __restrict__ boxes, const float* __restrict__ rot,
    const float* __restrict__ tr, float* __restrict__ out) {
  const int b = blockIdx.x;
  const int tid = threadIdx.x;
  __shared__ u64 W[4096];

  for (int t = tid; t < 4096; t += 1024) {
    int c = t >> 7, r = t & 127;
    W[t] = (c < NCLS) ? merged[((size_t)b * 32 + c) * 128 + r] : 0ull;
  }
  __syncthreads();

  int active = 4096;
  #pragma unroll
  for (int level = 0; level < 5; ++level) {
    int npairs = active >> 8;
    for (int t = tid; t < npairs * 64; t += 1024) {
      int p = t >> 6, q = t & 63;
      int i1 = p * 256 + 128 + q, i2 = p * 256 + 255 - q;
      u64 a = W[i1]; W[i1] = W[i2]; W[i2] = a;
    }
    __syncthreads();
    for (int j = 128; j > 0; j >>= 1) {
      for (int i = tid; i < active; i += 1024) {
        int l = i ^ j;
        if (l > i) {
          u64 a = W[i], bb = W[l];
          if (a < bb) { W[i] = bb; W[l] = a; }
        }
      }
      __syncthreads();
    }
    int half = active >> 1;
    u64 t0 = 0, t1 = 0;
    if (tid < half) t0 = W[(tid >> 7) * 256 + (tid & 127)];
    int t2i = tid + 1024;
    if (t2i < half) t1 = W[(t2i >> 7) * 256 + (t2i & 127)];
    __syncthreads();
    if (tid < half) W[tid] = t0;
    if (t2i < half) W[t2i] = t1;
    __syncthreads();
    active = half;
  }

  if (tid < MAXDET) {
    u64 key = W[tid];
    bool valid = (key != 0ull);
    float* ob  = out + ((size_t)b * MAXDET + tid) * 4;
    float* os  = out + (size_t)BATCH * MAXDET * 4 + b * MAXDET + tid;
    float* ol  = os + BATCH * MAXDET;
    float* orr = out + (size_t)BATCH * MAXDET * 6 + ((size_t)b * MAXDET + tid) * 3;
    float* ot  = orr + (size_t)BATCH * MAXDET * 3;

    if (valid) {
      unsigned f = ~(unsigned)key;            // flat = c*K + r
      int cl = (int)(f / K);
      float sc = __uint_as_float((unsigned)(key >> 32) & 0x7FFFFFFFu);
      int orig = ws_i[(size_t)b * NCLS * K + f];
      const float* bp = boxes + ((size_t)b * NBOX + orig) * 4;
      ob[0] = bp[0]; ob[1] = bp[1]; ob[2] = bp[2]; ob[3] = bp[3];
      *os = sc;
      *ol = (float)cl;
      const float* rp = rot + ((size_t)b * NBOX + orig) * 3;
      orr[0] = rp[0]; orr[1] = rp[1]; orr[2] = rp[2];
      const float* tp = tr + ((size_t)b * NBOX + orig) * 3;
      ot[0] = tp[0]; ot[1] = tp[1]; ot[2] = tp[2];
    } else {
      ob[0] = ob[1] = ob[2] = ob[3] = -1.f;
      *os = -1.f; *ol = -1.f;
      orr[0] = orr[1] = orr[2] = -1.f;
      ot[0] = ot[1] = ot[2] = -1.f;
    }
  }
}

extern "C" void kernel_launch(void* const* d_in, const int* in_sizes, int n_in,
                              void* d_out, int out_size, void* d_ws, size_t ws_size,
                              hipStream_t stream) {
  const float* boxes = (const float*)d_in[0];
  const float* cls   = (const float*)d_in[1];
  const float* rot   = (const float*)d_in[2];
  const float* tr    = (const float*)d_in[3];
  float* out = (float*)d_out;

  char* ws = (char*)d_ws;
  u64*   coll   = (u64*)(ws + OFF_COLL);
  int*   cnt    = (int*)(ws + OFF_CNT);
  int*   ws_i   = (int*)(ws + OFF_WSI);
  u64*   merged = (u64*)(ws + OFF_MERGE);

  hipMemsetAsync(cnt, 0, BATCH * NCLS * sizeof(int), stream);
  collect_kernel<<<BATCH * CHUNKS, 512, 0, stream>>>(cls, cnt, coll);
  fused_sort_nms_kernel<<<BATCH * NCLS, 512, 0, stream>>>(coll, cnt, cls, boxes,
                                                          ws_i, merged);
  merge_gather_kernel<<<BATCH, 1024, 0, stream>>>(merged, ws_i, boxes, rot, tr, out);
}

// Round 9
// 103.533 us; speedup vs baseline: 1.6972x; 1.1334x over previous
//
#include <hip/hip_runtime.h>
#include <math.h>

typedef unsigned long long u64;

#define BATCH 16
#define NBOX 100000
#define NCLS 30
#define K 200            // PRE_NMS_TOPK
#define MAXDET 100
#define SCORE_THR 0.01f
#define NMS_THR 0.5f
#define T0 0.995f        // static collect threshold; inline fallback guarantees exactness

#define ELEM_PER_BATCH (NBOX * NCLS)              // 3,000,000
#define CAP 1024
#define CHUNKS 48                                 // chunks per batch
#define VEC_PER_CHUNK 15625                       // 750000 vec4 per batch / 48
#define SEG 48                                    // per-class per-chunk slot segment
#define OVF 1000000                               // overflow marker in pcnt

// workspace layout (bytes)
#define OFF_COLL   0ull                                            // u64[480][48][48]
#define OFF_PCNT   (OFF_COLL + (size_t)BATCH*NCLS*CHUNKS*SEG*8)    // int[768][32]
#define OFF_WSI    (OFF_PCNT + (size_t)BATCH*CHUNKS*32*4)          // int[480*200]
#define OFF_MERGE  (OFF_WSI + (size_t)BATCH*NCLS*K*4)              // u64[16][32][128]

// ---------------------------------------------------------------------------
// 1) Single coalesced pass: collect entries > T0 into per-class LDS buffers
//    (LDS atomics only). Each block owns a deterministic global segment —
//    NO global atomics, NO counter memset needed.
// ---------------------------------------------------------------------------
__global__ __launch_bounds__(512) void collect_kernel(const float* __restrict__ cls,
                                                      int* __restrict__ pcnt,
                                                      u64* __restrict__ coll) {
  const int b = blockIdx.x / CHUNKS;
  const int chunk = blockIdx.x % CHUNKS;
  const int tid = threadIdx.x;

  __shared__ u64 lbuf[NCLS][SEG];
  __shared__ int lcnt[NCLS];

  if (tid < NCLS) lcnt[tid] = 0;
  __syncthreads();

  const int vbase = chunk * VEC_PER_CHUNK;   // vec4 index within batch
  const float4* p = (const float4*)(cls + (size_t)b * ELEM_PER_BATCH) + vbase;

  auto process = [&](float4 v, int idx) {
    float m = fmaxf(fmaxf(v.x, v.y), fmaxf(v.z, v.w));
    if (m > T0) {                            // rare (~2% of vec4s)
      float vv[4] = {v.x, v.y, v.z, v.w};
      #pragma unroll
      for (int j = 0; j < 4; ++j) {
        if (vv[j] > T0) {
          int e = (vbase + idx) * 4 + j;     // element within batch (< 3M)
          int c = e % NCLS;
          int n = e / NCLS;
          int pos = atomicAdd(&lcnt[c], 1);  // LDS atomic — cheap
          if (pos < SEG)
            lbuf[c][pos] = ((u64)__float_as_uint(vv[j]) << 32) | (unsigned)(~(unsigned)n);
        }
      }
    }
  };

  int i = tid;
  for (; i + 1536 < VEC_PER_CHUNK; i += 2048) {
    float4 a  = p[i];
    float4 b2 = p[i + 512];
    float4 c2 = p[i + 1024];
    float4 d2 = p[i + 1536];
    process(a,  i);
    process(b2, i + 512);
    process(c2, i + 1024);
    process(d2, i + 1536);
  }
  for (; i < VEC_PER_CHUNK; i += 512) process(p[i], i);
  __syncthreads();

  if (tid < NCLS) {
    int m = lcnt[tid];
    pcnt[(b * CHUNKS + chunk) * 32 + tid] = (m > SEG) ? OVF : m;
    lcnt[tid] = (m < SEG) ? m : SEG;
  }
  __syncthreads();

  // flush: block's own deterministic segment per class
  for (int t = tid; t < NCLS * SEG; t += 512) {
    int c = t / SEG, s = t - (t / SEG) * SEG;
    if (s < lcnt[c])
      coll[((size_t)(b * NCLS + c) * CHUNKS + chunk) * SEG + s] = lbuf[c][s];
  }
}

// ---------------------------------------------------------------------------
// 2) Fused: gather segments -> sort -> top-200 -> bitmask NMS -> compaction ->
//    emit sorted per-class key list (top-128). Sort width adapts (512/1024).
//    Bad (b,c) [overflow, total<K or total>CAP]: inline exact radix-select.
// ---------------------------------------------------------------------------
__global__ __launch_bounds__(512) void fused_sort_nms_kernel(
    const u64* __restrict__ coll, const int* __restrict__ pcnt,
    const float* __restrict__ cls, const float* __restrict__ boxes,
    int* __restrict__ ws_i, u64* __restrict__ merged) {
  const int bc = blockIdx.x;
  const int b = bc / NCLS, c = bc % NCLS;
  const int tid = threadIdx.x;

  __shared__ u64 arr[CAP];                 // good path: sort buffer; bad path: hist overlay
  __shared__ float sx1[K], sy1[K], sx2[K], sy2[K], sarea[K], ss[K];
  __shared__ int sidx[K];
  __shared__ unsigned mask[K][8];
  __shared__ unsigned keepw[8];
  __shared__ int s_surv;
  __shared__ u64 comb[256];
  __shared__ unsigned eqbuf[512];
  __shared__ unsigned s_pref, s_mask, s_krem, s_takeall;
  __shared__ unsigned s_cntgt, s_cnteq;
  __shared__ int scnt[CHUNKS], soff[CHUNKS];
  __shared__ int s_total, s_bad;

  if (tid < CHUNKS) scnt[tid] = pcnt[(b * CHUNKS + tid) * 32 + c];
  __syncthreads();
  if (tid == 0) {
    int tot = 0, bad = 0;
    for (int ch = 0; ch < CHUNKS; ++ch) {
      int v = scnt[ch];
      if (v > SEG) bad = 1;
      soff[ch] = tot;
      tot += v;
    }
    if (tot < K || tot > CAP) bad = 1;
    s_total = tot; s_bad = bad;
  }
  __syncthreads();
  const bool bad = (s_bad != 0);

  if (!bad) {
    const int N = (s_total <= 512) ? 512 : CAP;   // block-uniform -> barrier-safe
    for (int i = tid; i < N; i += 512) arr[i] = 0ull;
    __syncthreads();
    for (int t = tid; t < CHUNKS * SEG; t += 512) {
      int ch = t / SEG, s = t - (t / SEG) * SEG;
      if (s < scnt[ch])
        arr[soff[ch] + s] = coll[((size_t)bc * CHUNKS + ch) * SEG + s];
    }
    for (int k = 2; k <= N; k <<= 1) {
      for (int j = k >> 1; j > 0; j >>= 1) {
        __syncthreads();
        for (int i = tid; i < N; i += 512) {
          int l = i ^ j;
          if (l > i) {
            u64 a = arr[i], bb = arr[l];
            bool up = ((i & k) == 0);
            if (up ? (a < bb) : (a > bb)) { arr[i] = bb; arr[l] = a; }
          }
        }
      }
    }
    __syncthreads();
    for (int r = tid; r < K; r += 512) {
      u64 e = arr[r];
      float s = (e != 0ull) ? __uint_as_float((unsigned)(e >> 32)) : -INFINITY;
      int idx = (e != 0ull) ? (int)(~(unsigned)e) : 0;
      ss[r] = s; sidx[r] = idx;
      ws_i[bc * K + r] = idx;
    }
  } else {
    // ---- inline exact radix select over the strided class column ----
    unsigned (*hist)[256] = (unsigned (*)[256])arr;   // 8 waves x 256 bins = 8KB
    const int wv = tid >> 6;
    if (tid == 0) { s_pref = 0u; s_mask = 0u; s_krem = K; s_takeall = 0u; }
    __syncthreads();
    const float* col = cls + (size_t)b * NBOX * NCLS + c;

    for (int pass = 0; pass < 4; ++pass) {
      if (s_takeall) break;
      const int shift = 24 - 8 * pass;
      for (int i = tid; i < 8 * 256; i += 512) ((unsigned*)hist)[i] = 0u;
      __syncthreads();
      const unsigned pref = s_pref, msk = s_mask;
      for (int n = tid; n < NBOX; n += 512) {
        float v = col[(size_t)n * NCLS];
        if (v > SCORE_THR) {
          unsigned key = __float_as_uint(v);
          if ((key & msk) == pref)
            atomicAdd(&hist[wv][(key >> shift) & 0xFFu], 1u);
        }
      }
      __syncthreads();
      if (tid < 256) {
        unsigned t2 = 0;
        for (int w = 0; w < 8; ++w) t2 += hist[w][tid];
        hist[0][tid] = t2;
      }
      __syncthreads();
      if (tid == 0) {
        unsigned krem = s_krem, cum = 0; int dsel = -1;
        for (int d = 255; d >= 0; --d) {
          unsigned cc = hist[0][d];
          if (cum + cc >= krem) { dsel = d; break; }
          cum += cc;
        }
        if (dsel < 0) s_takeall = 1u;
        else {
          s_krem = krem - cum;
          s_pref = pref | ((unsigned)dsel << shift);
          s_mask = msk | (0xFFu << shift);
        }
      }
      __syncthreads();
    }

    if (tid == 0) { s_cntgt = 0u; s_cnteq = 0u; }
    __syncthreads();
    const unsigned pivot = s_pref;
    const unsigned takeall = s_takeall;

    for (int n = tid; n < NBOX; n += 512) {
      float v = col[(size_t)n * NCLS];
      if (v > SCORE_THR) {
        unsigned key = __float_as_uint(v);
        if (takeall || key > pivot) {
          unsigned pos = atomicAdd(&s_cntgt, 1u);
          if (pos < 256u)
            comb[pos] = ((u64)key << 32) | (unsigned)(~(unsigned)n);
        } else if (key == pivot) {
          unsigned pos = atomicAdd(&s_cnteq, 1u);
          if (pos < 512u) eqbuf[pos] = (unsigned)n;
        }
      }
    }
    __syncthreads();
    const unsigned cntgt = (s_cntgt < 256u) ? s_cntgt : 256u;
    const unsigned cnteq = (s_cnteq < 512u) ? s_cnteq : 512u;
    unsigned need = 0;
    if (!takeall) {
      need = (cntgt < (unsigned)K) ? ((unsigned)K - cntgt) : 0u;
      if (need > cnteq) need = cnteq;
    }
    for (int i = tid; i < 512; i += 512)
      if ((unsigned)i >= cnteq) eqbuf[i] = 0xFFFFFFFFu;
    for (int k = 2; k <= 512; k <<= 1) {
      for (int j = k >> 1; j > 0; j >>= 1) {
        __syncthreads();
        {
          int i = tid, l = i ^ j;
          if (l > i) {
            unsigned a = eqbuf[i], bb = eqbuf[l];
            bool up = ((i & k) == 0);
            if (up ? (a > bb) : (a < bb)) { eqbuf[i] = bb; eqbuf[l] = a; }
          }
        }
      }
    }
    __syncthreads();
    for (int t = tid; t < (int)need; t += 512)
      comb[cntgt + t] = ((u64)pivot << 32) | (unsigned)(~eqbuf[t]);
    const unsigned M = cntgt + need;
    for (int i = tid; i < 256; i += 512)
      if ((unsigned)i >= M) comb[i] = 0ull;
    for (int k = 2; k <= 256; k <<= 1) {
      for (int j = k >> 1; j > 0; j >>= 1) {
        __syncthreads();
        if (tid < 256) {
          int i = tid, l = i ^ j;
          if (l > i) {
            u64 a = comb[i], bb = comb[l];
            bool up = ((i & k) == 0);
            if (up ? (a < bb) : (a > bb)) { comb[i] = bb; comb[l] = a; }
          }
        }
      }
    }
    __syncthreads();
    if (tid < K) {
      if ((unsigned)tid < M) {
        u64 e = comb[tid];
        ss[tid] = __uint_as_float((unsigned)(e >> 32));
        sidx[tid] = (int)(~(unsigned)e);
      } else {
        ss[tid] = -INFINITY;
        sidx[tid] = 0;
      }
      ws_i[bc * K + tid] = sidx[tid];
    }
  }
  for (int i = tid; i < K * 8; i += 512) ((unsigned*)mask)[i] = 0u;
  if (tid < 8) keepw[tid] = 0u;
  __syncthreads();

  for (int r = tid; r < K; r += 512) {
    float s = ss[r];
    bool valid = (s != -INFINITY);
    float x1 = 0.f, y1 = 0.f, x2 = 0.f, y2 = 0.f;
    if (valid) {
      const float* bp = boxes + ((size_t)b * NBOX + sidx[r]) * 4;
      x1 = bp[0]; y1 = bp[1]; x2 = bp[2]; y2 = bp[3];
      atomicOr(&keepw[r >> 5], 1u << (r & 31));
    }
    sx1[r] = x1; sy1[r] = y1; sx2[r] = x2; sy2[r] = y2;
    sarea[r] = fmaxf(x2 - x1, 0.f) * fmaxf(y2 - y1, 0.f);
  }
  __syncthreads();

  // pairwise suppression bitmask, j > i (fully parallel, no barriers)
  for (int t = tid; t < K * K; t += 512) {
    int i = t / K, j = t - i * K;
    if (j > i) {
      float xx1 = fmaxf(sx1[i], sx1[j]);
      float yy1 = fmaxf(sy1[i], sy1[j]);
      float xx2 = fminf(sx2[i], sx2[j]);
      float yy2 = fminf(sy2[i], sy2[j]);
      float inter = fmaxf(xx2 - xx1, 0.f) * fmaxf(yy2 - yy1, 0.f);
      float uni = sarea[i] + sarea[j] - inter;
      float iou = inter / fmaxf(uni, 1e-8f);
      if (iou > NMS_THR) atomicOr(&mask[i][j >> 5], 1u << (j & 31));
    }
  }
  __syncthreads();

  // serial greedy scan on wave 0 (wave-synchronous, no barriers)
  if (tid < 64) {
    int w = tid & 7;
    unsigned keep = keepw[w];
    for (int i = 0; i < K; ++i) {
      unsigned kw = __shfl(keep, i >> 5, 64);
      if ((kw >> (i & 31)) & 1u)
        keep &= ~mask[i][w];
    }
    if (tid < 8) keepw[tid] = keep;
  }
  __syncthreads();

  // stable compaction + key emission (per-class list is sorted desc by key)
  for (int r = tid; r < K; r += 512) {
    int w6 = r >> 5, bit = r & 31;
    if ((keepw[w6] >> bit) & 1u) {
      int pos = 0;
      #pragma unroll
      for (int w = 0; w < 7; ++w) {
        unsigned kw = keepw[w];
        if (w < w6) pos += __popc(kw);
        else if (w == w6) pos += __popc(kw & ((1u << bit) - 1u));
      }
      if (pos < 128) {
        unsigned ord = __float_as_uint(ss[r]) | 0x80000000u;
        merged[((size_t)b * 32 + c) * 128 + pos] =
          ((u64)ord << 32) | (unsigned)(~(unsigned)(c * K + r));
      }
    }
  }
  if (tid == 0) {
    int S = 0;
    #pragma unroll
    for (int w = 0; w < 7; ++w) S += __popc(keepw[w]);
    s_surv = S;
  }
  __syncthreads();
  for (int t = s_surv + tid; t < 128; t += 512)
    merged[((size_t)b * 32 + c) * 128 + t] = 0ull;
}

// ---------------------------------------------------------------------------
// 3) Per-image merge tournament via merge-path: 32 sorted desc lists of 128
//    -> 5 levels of pairwise top-128 merges (exact; keys distinct) -> gather.
// ---------------------------------------------------------------------------
__device__ __forceinline__ int merge_path_128(const u64* __restrict__ A,
                                              const u64* __restrict__ B, int diag) {
  int lo = 0, hi = diag;          // diag <= 127 so indices stay in range
  while (lo < hi) {
    int mid = (lo + hi) >> 1;
    if (A[mid] >= B[diag - 1 - mid]) lo = mid + 1; else hi = mid;
  }
  return lo;
}

__global__ __launch_bounds__(1024) void merge_gather_kernel(
    const u64* __restrict__ merged, const int* __restrict__ ws_i,
    const float* __restrict__ boxes, const float* __restrict__ rot,
    const float* __restrict__ tr, float* __restrict__ out) {
  const int b = blockIdx.x;
  const int tid = threadIdx.x;
  __shared__ u64 S0[32 * 128];    // 32 KB
  __shared__ u64 S1[16 * 128];    // 16 KB

  for (int t = tid; t < 4096; t += 1024) {
    int c = t >> 7, r = t & 127;
    S0[t] = (c < NCLS) ? merged[((size_t)b * 32 + c) * 128 + r] : 0ull;
  }
  __syncthreads();

  #pragma unroll
  for (int level = 0; level < 5; ++level) {
    const int npairs = 16 >> level;
    const int nout = npairs * 128;
    const u64* src = (level & 1) ? S1 : S0;
    u64* dst = (level & 1) ? S0 : S1;
    for (int t = tid; t < nout; t += 1024) {
      int p = t >> 7, r = t & 127;
      const u64* A = src + (2 * p) * 128;
      const u64* B = src + (2 * p + 1) * 128;
      int i = merge_path_128(A, B, r);
      int j = r - i;
      u64 a = A[i], bb = B[j];
      dst[p * 128 + r] = (a >= bb) ? a : bb;
    }
    __syncthreads();
  }
  // result (top-128 desc) is in S1 (level 4 wrote dst = S1, lists 0)

  if (tid < MAXDET) {
    u64 key = S1[tid];
    bool valid = (key != 0ull);
    float* ob  = out + ((size_t)b * MAXDET + tid) * 4;
    float* os  = out + (size_t)BATCH * MAXDET * 4 + b * MAXDET + tid;
    float* ol  = os + BATCH * MAXDET;
    float* orr = out + (size_t)BATCH * MAXDET * 6 + ((size_t)b * MAXDET + tid) * 3;
    float* ot  = orr + (size_t)BATCH * MAXDET * 3;

    if (valid) {
      unsigned f = ~(unsigned)key;            // flat = c*K + r
      int cl = (int)(f / K);
      float sc = __uint_as_float((unsigned)(key >> 32) & 0x7FFFFFFFu);
      int orig = ws_i[(size_t)b * NCLS * K + f];
      const float* bp = boxes + ((size_t)b * NBOX + orig) * 4;
      ob[0] = bp[0]; ob[1] = bp[1]; ob[2] = bp[2]; ob[3] = bp[3];
      *os = sc;
      *ol = (float)cl;
      const float* rp = rot + ((size_t)b * NBOX + orig) * 3;
      orr[0] = rp[0]; orr[1] = rp[1]; orr[2] = rp[2];
      const float* tp = tr + ((size_t)b * NBOX + orig) * 3;
      ot[0] = tp[0]; ot[1] = tp[1]; ot[2] = tp[2];
    } else {
      ob[0] = ob[1] = ob[2] = ob[3] = -1.f;
      *os = -1.f; *ol = -1.f;
      orr[0] = orr[1] = orr[2] = -1.f;
      ot[0] = ot[1] = ot[2] = -1.f;
    }
  }
}

extern "C" void kernel_launch(void* const* d_in, const int* in_sizes, int n_in,
                              void* d_out, int out_size, void* d_ws, size_t ws_size,
                              hipStream_t stream) {
  const float* boxes = (const float*)d_in[0];
  const float* cls   = (const float*)d_in[1];
  const float* rot   = (const float*)d_in[2];
  const float* tr    = (const float*)d_in[3];
  float* out = (float*)d_out;

  char* ws = (char*)d_ws;
  u64*   coll   = (u64*)(ws + OFF_COLL);
  int*   pcnt   = (int*)(ws + OFF_PCNT);
  int*   ws_i   = (int*)(ws + OFF_WSI);
  u64*   merged = (u64*)(ws + OFF_MERGE);

  collect_kernel<<<BATCH * CHUNKS, 512, 0, stream>>>(cls, pcnt, coll);
  fused_sort_nms_kernel<<<BATCH * NCLS, 512, 0, stream>>>(coll, pcnt, cls, boxes,
                                                          ws_i, merged);
  merge_gather_kernel<<<BATCH, 1024, 0, stream>>>(merged, ws_i, boxes, rot, tr, out);
}

// Round 10
// 92.902 us; speedup vs baseline: 1.8914x; 1.1144x over previous
//
#include <hip/hip_runtime.h>
#include <math.h>

typedef unsigned long long u64;

#define BATCH 16
#define NBOX 100000
#define NCLS 30
#define K 200            // PRE_NMS_TOPK
#define MAXDET 100
#define SCORE_THR 0.01f
#define NMS_THR 0.5f
#define T0 0.995f        // static collect threshold; inline fallback guarantees exactness

#define ELEM_PER_BATCH (NBOX * NCLS)              // 3,000,000
#define CAP 1024
#define CHUNKS 48                                 // chunks per batch
#define VEC_PER_CHUNK 15625                       // 750000 vec4 per batch / 48
#define SEG 48                                    // per-class per-chunk slot segment
#define OVF 1000000                               // overflow marker in pcnt

// workspace layout (bytes)
#define OFF_COLL   0ull                                            // u64[480][48][48]
#define OFF_PCNT   (OFF_COLL + (size_t)BATCH*NCLS*CHUNKS*SEG*8)    // int[768][32]
#define OFF_WSI    (OFF_PCNT + (size_t)BATCH*CHUNKS*32*4)          // int[480*200]
#define OFF_MERGE  (OFF_WSI + (size_t)BATCH*NCLS*K*4)              // u64[16][32][128]

// ---------------------------------------------------------------------------
// 1) Single coalesced pass: collect entries > T0 into per-class LDS buffers
//    (LDS atomics only). Deterministic per-block segments — no global atomics,
//    no counter memset. (Unchanged from round 9.)
// ---------------------------------------------------------------------------
__global__ __launch_bounds__(512) void collect_kernel(const float* __restrict__ cls,
                                                      int* __restrict__ pcnt,
                                                      u64* __restrict__ coll) {
  const int b = blockIdx.x / CHUNKS;
  const int chunk = blockIdx.x % CHUNKS;
  const int tid = threadIdx.x;

  __shared__ u64 lbuf[NCLS][SEG];
  __shared__ int lcnt[NCLS];

  if (tid < NCLS) lcnt[tid] = 0;
  __syncthreads();

  const int vbase = chunk * VEC_PER_CHUNK;   // vec4 index within batch
  const float4* p = (const float4*)(cls + (size_t)b * ELEM_PER_BATCH) + vbase;

  auto process = [&](float4 v, int idx) {
    float m = fmaxf(fmaxf(v.x, v.y), fmaxf(v.z, v.w));
    if (m > T0) {                            // rare (~2% of vec4s)
      float vv[4] = {v.x, v.y, v.z, v.w};
      #pragma unroll
      for (int j = 0; j < 4; ++j) {
        if (vv[j] > T0) {
          int e = (vbase + idx) * 4 + j;     // element within batch (< 3M)
          int c = e % NCLS;
          int n = e / NCLS;
          int pos = atomicAdd(&lcnt[c], 1);  // LDS atomic — cheap
          if (pos < SEG)
            lbuf[c][pos] = ((u64)__float_as_uint(vv[j]) << 32) | (unsigned)(~(unsigned)n);
        }
      }
    }
  };

  int i = tid;
  for (; i + 1536 < VEC_PER_CHUNK; i += 2048) {
    float4 a  = p[i];
    float4 b2 = p[i + 512];
    float4 c2 = p[i + 1024];
    float4 d2 = p[i + 1536];
    process(a,  i);
    process(b2, i + 512);
    process(c2, i + 1024);
    process(d2, i + 1536);
  }
  for (; i < VEC_PER_CHUNK; i += 512) process(p[i], i);
  __syncthreads();

  if (tid < NCLS) {
    int m = lcnt[tid];
    pcnt[(b * CHUNKS + chunk) * 32 + tid] = (m > SEG) ? OVF : m;
    lcnt[tid] = (m < SEG) ? m : SEG;
  }
  __syncthreads();

  for (int t = tid; t < NCLS * SEG; t += 512) {
    int c = t / SEG, s = t - (t / SEG) * SEG;
    if (s < lcnt[c])
      coll[((size_t)(b * NCLS + c) * CHUNKS + chunk) * SEG + s] = lbuf[c][s];
  }
}

// ---------------------------------------------------------------------------
// 2) Fused: gather segments -> hybrid sort (wave-register bitonic-64 +
//    merge-path levels) -> top-200 -> bitmask NMS -> compaction -> emission.
//    Bad (b,c): inline exact radix-select (unchanged).
// ---------------------------------------------------------------------------
__global__ __launch_bounds__(512) void fused_sort_nms_kernel(
    const u64* __restrict__ coll, const int* __restrict__ pcnt,
    const float* __restrict__ cls, const float* __restrict__ boxes,
    int* __restrict__ ws_i, u64* __restrict__ merged) {
  const int bc = blockIdx.x;
  const int b = bc / NCLS, c = bc % NCLS;
  const int tid = threadIdx.x;

  __shared__ u64 arr[CAP];                 // good: sort buf A; bad: hist overlay
  __shared__ u64 arr2[CAP];                // good: sort buf B (ping-pong)
  __shared__ float sx1[K], sy1[K], sx2[K], sy2[K], sarea[K], ss[K];
  __shared__ int sidx[K];
  __shared__ unsigned mask[K][8];
  __shared__ unsigned keepw[8];
  __shared__ int s_surv;
  __shared__ u64 comb[256];
  __shared__ unsigned eqbuf[512];
  __shared__ unsigned s_pref, s_mask, s_krem, s_takeall;
  __shared__ unsigned s_cntgt, s_cnteq;
  __shared__ int scnt[CHUNKS], soff[CHUNKS];
  __shared__ int s_total, s_bad;

  if (tid < CHUNKS) scnt[tid] = pcnt[(b * CHUNKS + tid) * 32 + c];
  __syncthreads();
  if (tid == 0) {
    int tot = 0, bad = 0;
    for (int ch = 0; ch < CHUNKS; ++ch) {
      int v = scnt[ch];
      if (v > SEG) bad = 1;
      soff[ch] = tot;
      tot += v;
    }
    if (tot < K || tot > CAP) bad = 1;
    s_total = tot; s_bad = bad;
  }
  __syncthreads();
  const bool bad = (s_bad != 0);

  if (!bad) {
    const int N = (s_total <= 512) ? 512 : CAP;   // block-uniform -> barrier-safe
    for (int i = tid; i < N; i += 512) arr[i] = 0ull;
    __syncthreads();
    for (int t = tid; t < CHUNKS * SEG; t += 512) {
      int ch = t / SEG, s = t - (t / SEG) * SEG;
      if (s < scnt[ch])
        arr[soff[ch] + s] = coll[((size_t)bc * CHUNKS + ch) * SEG + s];
    }
    __syncthreads();

    // (a) wave-register descending bitonic sort of each 64-run (no barriers)
    {
      const int lane = tid & 63, w = tid >> 6;
      for (int run = w; run < (N >> 6); run += 8) {
        u64 v = arr[(run << 6) + lane];
        #pragma unroll
        for (int k = 2; k <= 64; k <<= 1) {
          #pragma unroll
          for (int j = k >> 1; j > 0; j >>= 1) {
            u64 o = __shfl_xor(v, j, 64);
            bool up = ((lane & k) == 0);
            bool lower = ((lane & j) == 0);
            u64 mn = (v < o) ? v : o;
            u64 mx = (v < o) ? o : v;
            v = (up != lower) ? mn : mx;     // descending orientation
          }
        }
        arr[(run << 6) + lane] = v;
      }
    }
    __syncthreads();

    // (b) merge-path levels: sorted-desc runs of L -> 2L (exact; A-first ties)
    u64* src = arr;
    u64* dst = arr2;
    for (int L = 64; L < N; L <<= 1) {
      const int twoL = L << 1;
      for (int t = tid; t < N; t += 512) {
        int pair = t / twoL;
        int diag = t - pair * twoL;
        const u64* A = src + pair * twoL;
        const u64* B = A + L;
        int lo = (diag > L) ? (diag - L) : 0;
        int hi = (diag < L) ? diag : L;
        while (lo < hi) {
          int mid = (lo + hi) >> 1;
          if (A[mid] >= B[diag - 1 - mid]) lo = mid + 1; else hi = mid;
        }
        int i2 = lo, j2 = diag - lo;
        u64 av = (i2 < L) ? A[i2] : 0ull;
        u64 bv = (j2 < L) ? B[j2] : 0ull;
        dst[t] = (i2 < L && (j2 >= L || av >= bv)) ? av : bv;
      }
      __syncthreads();
      u64* tmp = src; src = dst; dst = tmp;
    }

    for (int r = tid; r < K; r += 512) {
      u64 e = src[r];
      float s = (e != 0ull) ? __uint_as_float((unsigned)(e >> 32)) : -INFINITY;
      int idx = (e != 0ull) ? (int)(~(unsigned)e) : 0;
      ss[r] = s; sidx[r] = idx;
      ws_i[bc * K + r] = idx;
    }
  } else {
    // ---- inline exact radix select over the strided class column ----
    unsigned (*hist)[256] = (unsigned (*)[256])arr;   // 8 waves x 256 bins = 8KB
    const int wv = tid >> 6;
    if (tid == 0) { s_pref = 0u; s_mask = 0u; s_krem = K; s_takeall = 0u; }
    __syncthreads();
    const float* col = cls + (size_t)b * NBOX * NCLS + c;

    for (int pass = 0; pass < 4; ++pass) {
      if (s_takeall) break;
      const int shift = 24 - 8 * pass;
      for (int i = tid; i < 8 * 256; i += 512) ((unsigned*)hist)[i] = 0u;
      __syncthreads();
      const unsigned pref = s_pref, msk = s_mask;
      for (int n = tid; n < NBOX; n += 512) {
        float v = col[(size_t)n * NCLS];
        if (v > SCORE_THR) {
          unsigned key = __float_as_uint(v);
          if ((key & msk) == pref)
            atomicAdd(&hist[wv][(key >> shift) & 0xFFu], 1u);
        }
      }
      __syncthreads();
      if (tid < 256) {
        unsigned t2 = 0;
        for (int w = 0; w < 8; ++w) t2 += hist[w][tid];
        hist[0][tid] = t2;
      }
      __syncthreads();
      if (tid == 0) {
        unsigned krem = s_krem, cum = 0; int dsel = -1;
        for (int d = 255; d >= 0; --d) {
          unsigned cc = hist[0][d];
          if (cum + cc >= krem) { dsel = d; break; }
          cum += cc;
        }
        if (dsel < 0) s_takeall = 1u;
        else {
          s_krem = krem - cum;
          s_pref = pref | ((unsigned)dsel << shift);
          s_mask = msk | (0xFFu << shift);
        }
      }
      __syncthreads();
    }

    if (tid == 0) { s_cntgt = 0u; s_cnteq = 0u; }
    __syncthreads();
    const unsigned pivot = s_pref;
    const unsigned takeall = s_takeall;

    for (int n = tid; n < NBOX; n += 512) {
      float v = col[(size_t)n * NCLS];
      if (v > SCORE_THR) {
        unsigned key = __float_as_uint(v);
        if (takeall || key > pivot) {
          unsigned pos = atomicAdd(&s_cntgt, 1u);
          if (pos < 256u)
            comb[pos] = ((u64)key << 32) | (unsigned)(~(unsigned)n);
        } else if (key == pivot) {
          unsigned pos = atomicAdd(&s_cnteq, 1u);
          if (pos < 512u) eqbuf[pos] = (unsigned)n;
        }
      }
    }
    __syncthreads();
    const unsigned cntgt = (s_cntgt < 256u) ? s_cntgt : 256u;
    const unsigned cnteq = (s_cnteq < 512u) ? s_cnteq : 512u;
    unsigned need = 0;
    if (!takeall) {
      need = (cntgt < (unsigned)K) ? ((unsigned)K - cntgt) : 0u;
      if (need > cnteq) need = cnteq;
    }
    for (int i = tid; i < 512; i += 512)
      if ((unsigned)i >= cnteq) eqbuf[i] = 0xFFFFFFFFu;
    for (int k = 2; k <= 512; k <<= 1) {
      for (int j = k >> 1; j > 0; j >>= 1) {
        __syncthreads();
        {
          int i = tid, l = i ^ j;
          if (l > i) {
            unsigned a = eqbuf[i], bb = eqbuf[l];
            bool up = ((i & k) == 0);
            if (up ? (a > bb) : (a < bb)) { eqbuf[i] = bb; eqbuf[l] = a; }
          }
        }
      }
    }
    __syncthreads();
    for (int t = tid; t < (int)need; t += 512)
      comb[cntgt + t] = ((u64)pivot << 32) | (unsigned)(~eqbuf[t]);
    const unsigned M = cntgt + need;
    for (int i = tid; i < 256; i += 512)
      if ((unsigned)i >= M) comb[i] = 0ull;
    for (int k = 2; k <= 256; k <<= 1) {
      for (int j = k >> 1; j > 0; j >>= 1) {
        __syncthreads();
        if (tid < 256) {
          int i = tid, l = i ^ j;
          if (l > i) {
            u64 a = comb[i], bb = comb[l];
            bool up = ((i & k) == 0);
            if (up ? (a < bb) : (a > bb)) { comb[i] = bb; comb[l] = a; }
          }
        }
      }
    }
    __syncthreads();
    if (tid < K) {
      if ((unsigned)tid < M) {
        u64 e = comb[tid];
        ss[tid] = __uint_as_float((unsigned)(e >> 32));
        sidx[tid] = (int)(~(unsigned)e);
      } else {
        ss[tid] = -INFINITY;
        sidx[tid] = 0;
      }
      ws_i[bc * K + tid] = sidx[tid];
    }
  }
  for (int i = tid; i < K * 8; i += 512) ((unsigned*)mask)[i] = 0u;
  if (tid < 8) keepw[tid] = 0u;
  __syncthreads();

  for (int r = tid; r < K; r += 512) {
    float s = ss[r];
    bool valid = (s != -INFINITY);
    float x1 = 0.f, y1 = 0.f, x2 = 0.f, y2 = 0.f;
    if (valid) {
      const float* bp = boxes + ((size_t)b * NBOX + sidx[r]) * 4;
      x1 = bp[0]; y1 = bp[1]; x2 = bp[2]; y2 = bp[3];
      atomicOr(&keepw[r >> 5], 1u << (r & 31));
    }
    sx1[r] = x1; sy1[r] = y1; sx2[r] = x2; sy2[r] = y2;
    sarea[r] = fmaxf(x2 - x1, 0.f) * fmaxf(y2 - y1, 0.f);
  }
  __syncthreads();

  // pairwise suppression bitmask, j > i (fully parallel, no barriers)
  for (int t = tid; t < K * K; t += 512) {
    int i = t / K, j = t - i * K;
    if (j > i) {
      float xx1 = fmaxf(sx1[i], sx1[j]);
      float yy1 = fmaxf(sy1[i], sy1[j]);
      float xx2 = fminf(sx2[i], sx2[j]);
      float yy2 = fminf(sy2[i], sy2[j]);
      float inter = fmaxf(xx2 - xx1, 0.f) * fmaxf(yy2 - yy1, 0.f);
      float uni = sarea[i] + sarea[j] - inter;
      float iou = inter / fmaxf(uni, 1e-8f);
      if (iou > NMS_THR) atomicOr(&mask[i][j >> 5], 1u << (j & 31));
    }
  }
  __syncthreads();

  // serial greedy scan on wave 0 (wave-synchronous, no barriers)
  if (tid < 64) {
    int w = tid & 7;
    unsigned keep = keepw[w];
    for (int i = 0; i < K; ++i) {
      unsigned kw = __shfl(keep, i >> 5, 64);
      if ((kw >> (i & 31)) & 1u)
        keep &= ~mask[i][w];
    }
    if (tid < 8) keepw[tid] = keep;
  }
  __syncthreads();

  // stable compaction + key emission (per-class list is sorted desc by key)
  for (int r = tid; r < K; r += 512) {
    int w6 = r >> 5, bit = r & 31;
    if ((keepw[w6] >> bit) & 1u) {
      int pos = 0;
      #pragma unroll
      for (int w = 0; w < 7; ++w) {
        unsigned kw = keepw[w];
        if (w < w6) pos += __popc(kw);
        else if (w == w6) pos += __popc(kw & ((1u << bit) - 1u));
      }
      if (pos < 128) {
        unsigned ord = __float_as_uint(ss[r]) | 0x80000000u;
        merged[((size_t)b * 32 + c) * 128 + pos] =
          ((u64)ord << 32) | (unsigned)(~(unsigned)(c * K + r));
      }
    }
  }
  if (tid == 0) {
    int S = 0;
    #pragma unroll
    for (int w = 0; w < 7; ++w) S += __popc(keepw[w]);
    s_surv = S;
  }
  __syncthreads();
  for (int t = s_surv + tid; t < 128; t += 512)
    merged[((size_t)b * 32 + c) * 128 + t] = 0ull;
}

// ---------------------------------------------------------------------------
// 3) Per-image merge tournament via merge-path: 32 sorted desc lists of 128
//    -> 5 levels of pairwise top-128 merges (exact; keys distinct) -> gather.
// ---------------------------------------------------------------------------
__device__ __forceinline__ int merge_path_128(const u64* __restrict__ A,
                                              const u64* __restrict__ B, int diag) {
  int lo = 0, hi = diag;          // diag <= 127 so indices stay in range
  while (lo < hi) {
    int mid = (lo + hi) >> 1;
    if (A[mid] >= B[diag - 1 - mid]) lo = mid + 1; else hi = mid;
  }
  return lo;
}

__global__ __launch_bounds__(1024) void merge_gather_kernel(
    const u64* __restrict__ merged, const int* __restrict__ ws_i,
    const float* __restrict__ boxes, const float* __restrict__ rot,
    const float* __restrict__ tr, float* __restrict__ out) {
  const int b = blockIdx.x;
  const int tid = threadIdx.x;
  __shared__ u64 S0[32 * 128];    // 32 KB
  __shared__ u64 S1[16 * 128];    // 16 KB

  for (int t = tid; t < 4096; t += 1024) {
    int c = t >> 7, r = t & 127;
    S0[t] = (c < NCLS) ? merged[((size_t)b * 32 + c) * 128 + r] : 0ull;
  }
  __syncthreads();

  #pragma unroll
  for (int level = 0; level < 5; ++level) {
    const int npairs = 16 >> level;
    const int nout = npairs * 128;
    const u64* src = (level & 1) ? S1 : S0;
    u64* dst = (level & 1) ? S0 : S1;
    for (int t = tid; t < nout; t += 1024) {
      int p = t >> 7, r = t & 127;
      const u64* A = src + (2 * p) * 128;
      const u64* B = src + (2 * p + 1) * 128;
      int i = merge_path_128(A, B, r);
      int j = r - i;
      u64 a = A[i], bb = B[j];
      dst[p * 128 + r] = (a >= bb) ? a : bb;
    }
    __syncthreads();
  }

  if (tid < MAXDET) {
    u64 key = S1[tid];
    bool valid = (key != 0ull);
    float* ob  = out + ((size_t)b * MAXDET + tid) * 4;
    float* os  = out + (size_t)BATCH * MAXDET * 4 + b * MAXDET + tid;
    float* ol  = os + BATCH * MAXDET;
    float* orr = out + (size_t)BATCH * MAXDET * 6 + ((size_t)b * MAXDET + tid) * 3;
    float* ot  = orr + (size_t)BATCH * MAXDET * 3;

    if (valid) {
      unsigned f = ~(unsigned)key;            // flat = c*K + r
      int cl = (int)(f / K);
      float sc = __uint_as_float((unsigned)(key >> 32) & 0x7FFFFFFFu);
      int orig = ws_i[(size_t)b * NCLS * K + f];
      const float* bp = boxes + ((size_t)b * NBOX + orig) * 4;
      ob[0] = bp[0]; ob[1] = bp[1]; ob[2] = bp[2]; ob[3] = bp[3];
      *os = sc;
      *ol = (float)cl;
      const float* rp = rot + ((size_t)b * NBOX + orig) * 3;
      orr[0] = rp[0]; orr[1] = rp[1]; orr[2] = rp[2];
      const float* tp = tr + ((size_t)b * NBOX + orig) * 3;
      ot[0] = tp[0]; ot[1] = tp[1]; ot[2] = tp[2];
    } else {
      ob[0] = ob[1] = ob[2] = ob[3] = -1.f;
      *os = -1.f; *ol = -1.f;
      orr[0] = orr[1] = orr[2] = -1.f;
      ot[0] = ot[1] = ot[2] = -1.f;
    }
  }
}

extern "C" void kernel_launch(void* const* d_in, const int* in_sizes, int n_in,
                              void* d_out, int out_size, void* d_ws, size_t ws_size,
                              hipStream_t stream) {
  const float* boxes = (const float*)d_in[0];
  const float* cls   = (const float*)d_in[1];
  const float* rot   = (const float*)d_in[2];
  const float* tr    = (const float*)d_in[3];
  float* out = (float*)d_out;

  char* ws = (char*)d_ws;
  u64*   coll   = (u64*)(ws + OFF_COLL);
  int*   pcnt   = (int*)(ws + OFF_PCNT);
  int*   ws_i   = (int*)(ws + OFF_WSI);
  u64*   merged = (u64*)(ws + OFF_MERGE);

  collect_kernel<<<BATCH * CHUNKS, 512, 0, stream>>>(cls, pcnt, coll);
  fused_sort_nms_kernel<<<BATCH * NCLS, 512, 0, stream>>>(coll, pcnt, cls, boxes,
                                                          ws_i, merged);
  merge_gather_kernel<<<BATCH, 1024, 0, stream>>>(merged, ws_i, boxes, rot, tr, out);
}